// Round 2
// baseline (896.403 us; speedup 1.0000x reference)
//
#include <hip/hip_runtime.h>
#include <hip/hip_bf16.h>
#include <cstdint>

#define N 4096
#define DIM 128
#define WEIGHT 0.01f
#define EPSQ 1e-12f
#define MAXKEY 0xFFFFFFFFFFFFFFFFull

typedef unsigned long long u64;

// ---------------- K1: sq[i] = ||x_i||^2 (one wave per row) ----------------
__global__ void row_norms_kernel(const float* __restrict__ x, float* __restrict__ sq) {
    const int wave = threadIdx.x >> 6;
    const int lane = threadIdx.x & 63;
    const int row = blockIdx.x * 4 + wave;
    const float2 v = *reinterpret_cast<const float2*>(x + (size_t)row * DIM + lane * 2);
    float s = v.x * v.x + v.y * v.y;
    #pragma unroll
    for (int off = 32; off; off >>= 1) s += __shfl_xor(s, off);
    if (lane == 0) sq[row] = s;
}

// ------------- K2: D[i][j] = sqrt(max(sq_i + sq_j - 2 x_i.x_j, eps)) -------------
// block (16,16); each thread computes a 2x2 output quad. Bitwise-symmetric:
// D[i][j] and D[j][i] use identical FMA order -> identical bits.
__global__ void dist_matrix_kernel(const float* __restrict__ x,
                                   const float* __restrict__ sq,
                                   float* __restrict__ Dm) {
    const int tx = threadIdx.x, ty = threadIdx.y;
    const int j0 = blockIdx.x * 32 + tx, j1 = j0 + 16;
    const int i0 = blockIdx.y * 32 + ty, i1 = i0 + 16;
    const float4* A0 = reinterpret_cast<const float4*>(x + (size_t)i0 * DIM);
    const float4* A1 = reinterpret_cast<const float4*>(x + (size_t)i1 * DIM);
    const float4* B0 = reinterpret_cast<const float4*>(x + (size_t)j0 * DIM);
    const float4* B1 = reinterpret_cast<const float4*>(x + (size_t)j1 * DIM);
    float d00 = 0.f, d01 = 0.f, d10 = 0.f, d11 = 0.f;
    #pragma unroll
    for (int k = 0; k < DIM / 4; ++k) {
        const float4 a0 = A0[k], a1 = A1[k], b0 = B0[k], b1 = B1[k];
        d00 += a0.x * b0.x + a0.y * b0.y + a0.z * b0.z + a0.w * b0.w;
        d01 += a0.x * b1.x + a0.y * b1.y + a0.z * b1.z + a0.w * b1.w;
        d10 += a1.x * b0.x + a1.y * b0.y + a1.z * b0.z + a1.w * b0.w;
        d11 += a1.x * b1.x + a1.y * b1.y + a1.z * b1.z + a1.w * b1.w;
    }
    const float si0 = sq[i0], si1 = sq[i1], sj0 = sq[j0], sj1 = sq[j1];
    Dm[(size_t)i0 * N + j0] = sqrtf(fmaxf(si0 + sj0 - 2.f * d00, EPSQ));
    Dm[(size_t)i0 * N + j1] = sqrtf(fmaxf(si0 + sj1 - 2.f * d01, EPSQ));
    Dm[(size_t)i1 * N + j0] = sqrtf(fmaxf(si1 + sj0 - 2.f * d10, EPSQ));
    Dm[(size_t)i1 * N + j1] = sqrtf(fmaxf(si1 + sj1 - 2.f * d11, EPSQ));
}

// ---------------- K3: init Boruvka state ----------------
__global__ void init_kernel(int* __restrict__ comp, u64* __restrict__ best,
                            double* __restrict__ wsum) {
    const int i = blockIdx.x * 1024 + threadIdx.x;
    comp[i] = i;
    best[i] = MAXKEY;
    if (i == 0) *wsum = 0.0;
}

// ---------------- K4: per-row min outgoing edge -> atomicMin per component ----------------
// One wave per row. Key = (f32 weight bits << 32) | canonical_edge_id.
// Canonical id (min(i,j)<<12 | max(i,j)) gives a GLOBAL total order on
// undirected edges -> hook graph has only 2-cycles even with fp32 ties.
__global__ void scan_kernel(const float* __restrict__ Dm, const int* __restrict__ comp,
                            u64* __restrict__ best) {
    const int wave = threadIdx.x >> 6;
    const int lane = threadIdx.x & 63;
    const int i = blockIdx.x * 4 + wave;
    const int ci = comp[i];
    const float* row = Dm + (size_t)i * N;
    u64 m = MAXKEY;
    #pragma unroll
    for (int k = 0; k < N / 256; ++k) {
        const int j = k * 256 + lane * 4;
        const float4 d = *reinterpret_cast<const float4*>(row + j);
        const int4 cj = *reinterpret_cast<const int4*>(comp + j);
        const u64 id0 = (i < j + 0) ? (u64)((i << 12) | (j + 0)) : (u64)(((j + 0) << 12) | i);
        const u64 id1 = (i < j + 1) ? (u64)((i << 12) | (j + 1)) : (u64)(((j + 1) << 12) | i);
        const u64 id2 = (i < j + 2) ? (u64)((i << 12) | (j + 2)) : (u64)(((j + 2) << 12) | i);
        const u64 id3 = (i < j + 3) ? (u64)((i << 12) | (j + 3)) : (u64)(((j + 3) << 12) | i);
        const u64 k0 = (cj.x != ci) ? (((u64)__float_as_uint(d.x) << 32) | id0) : MAXKEY;
        const u64 k1 = (cj.y != ci) ? (((u64)__float_as_uint(d.y) << 32) | id1) : MAXKEY;
        const u64 k2 = (cj.z != ci) ? (((u64)__float_as_uint(d.z) << 32) | id2) : MAXKEY;
        const u64 k3 = (cj.w != ci) ? (((u64)__float_as_uint(d.w) << 32) | id3) : MAXKEY;
        const u64 m01 = k0 < k1 ? k0 : k1;
        const u64 m23 = k2 < k3 ? k2 : k3;
        const u64 mm = m01 < m23 ? m01 : m23;
        m = mm < m ? mm : m;
    }
    #pragma unroll
    for (int off = 32; off; off >>= 1) {
        const u64 o = __shfl_xor(m, off);
        m = o < m ? o : m;
    }
    if (lane == 0 && m != MAXKEY) atomicMin(&best[ci], m);
}

// ---------------- K5: single-block hook/merge/compress ----------------
__launch_bounds__(1024, 1)
__global__ void merge_kernel(u64* __restrict__ best, int* __restrict__ comp,
                             double* __restrict__ wsum, float* __restrict__ out,
                             int write_out) {
    __shared__ int parent[N];
    __shared__ double red[1024];
    const int tid = threadIdx.x;

    // --- hook: parent[c] = component of the other endpoint of best[c] ---
    u64 b[4];
    #pragma unroll
    for (int q = 0; q < 4; ++q) {
        const int c = tid + q * 1024;
        b[q] = best[c];
        int p = c;
        if (b[q] != MAXKEY) {
            const int id = (int)(b[q] & 0xFFFFFFu);
            const int a = id >> 12, e = id & 0xFFF;
            const int ca = comp[a], ce = comp[e];
            p = (ca == c) ? ce : ca;
        }
        parent[c] = p;
    }
    __syncthreads();

    // --- 2-cycle break (read pass, barrier, write pass: race-free) ---
    int np[4];
    #pragma unroll
    for (int q = 0; q < 4; ++q) {
        const int c = tid + q * 1024;
        const int p = parent[c];
        np[q] = (p != c && parent[p] == c && c < p) ? c : p;
    }
    __syncthreads();
    double myw = 0.0;
    #pragma unroll
    for (int q = 0; q < 4; ++q) {
        const int c = tid + q * 1024;
        parent[c] = np[q];
        if (np[q] != c) myw += (double)__uint_as_float((unsigned)(b[q] >> 32));
        best[c] = MAXKEY;  // reset for next round
    }

    // --- deterministic weight reduction (single block, fixed tree order) ---
    red[tid] = myw;
    __syncthreads();
    #pragma unroll
    for (int s = 512; s; s >>= 1) {
        if (tid < s) red[tid] += red[tid + s];
        __syncthreads();
    }

    // --- pointer jumping: 12 iters covers depth 4096 (read/write split) ---
    for (int it = 0; it < 12; ++it) {
        #pragma unroll
        for (int q = 0; q < 4; ++q) {
            const int c = tid + q * 1024;
            np[q] = parent[parent[c]];
        }
        __syncthreads();
        #pragma unroll
        for (int q = 0; q < 4; ++q) parent[tid + q * 1024] = np[q];
        __syncthreads();
    }

    // --- comp update: old root -> new root ---
    #pragma unroll
    for (int q = 0; q < 4; ++q) {
        const int i = tid + q * 1024;
        comp[i] = parent[comp[i]];
    }

    if (tid == 0) {
        const double w = *wsum + red[0];
        *wsum = w;
        if (write_out) out[0] = (float)(WEIGHT * w / (double)(N - 1));
    }
}

extern "C" void kernel_launch(void* const* d_in, const int* in_sizes, int n_in,
                              void* d_out, int out_size, void* d_ws, size_t ws_size,
                              hipStream_t stream) {
    const float* x = (const float*)d_in[0];
    char* ws = (char*)d_ws;
    float* Dm = (float*)ws;                                   // 64 MiB
    float* sq = (float*)(ws + (size_t)N * N * 4);             // 16 KiB
    int* comp = (int*)(ws + (size_t)N * N * 4 + 16384);       // 16 KiB
    u64* best = (u64*)(ws + (size_t)N * N * 4 + 32768);       // 32 KiB
    double* wsum = (double*)(ws + (size_t)N * N * 4 + 65536); // 8 B
    float* out = (float*)d_out;

    row_norms_kernel<<<N / 4, 256, 0, stream>>>(x, sq);
    dim3 blk(16, 16);
    dim3 grd(N / 32, N / 32);
    dist_matrix_kernel<<<grd, blk, 0, stream>>>(x, sq, Dm);
    init_kernel<<<4, 1024, 0, stream>>>(comp, best, wsum);
    for (int r = 0; r < 12; ++r) {
        scan_kernel<<<N / 4, 256, 0, stream>>>(Dm, comp, best);
        merge_kernel<<<1, 1024, 0, stream>>>(best, comp, wsum, out, r == 11 ? 1 : 0);
    }
}

// Round 3
// 361.214 us; speedup vs baseline: 2.4816x; 2.4816x over previous
//
#include <hip/hip_runtime.h>
#include <hip/hip_bf16.h>
#include <cstdint>

#define N 4096
#define DIM 128
#define WEIGHT 0.01f
#define EPSQ 1e-12f
#define MAXKEY 0xFFFFFFFFFFFFFFFFull

typedef unsigned long long u64;
typedef unsigned short u16;
typedef short short8 __attribute__((ext_vector_type(8)));
typedef u16 ushort8 __attribute__((ext_vector_type(8)));
typedef float f32x4 __attribute__((ext_vector_type(4)));

__device__ __forceinline__ u16 f32_to_bf16(float f) {
    const unsigned u = __float_as_uint(f);
    return (u16)((u + 0x7FFFu + ((u >> 16) & 1u)) >> 16);  // round-to-nearest-even
}

// ---------------- K0: convert x (f32) -> xb (bf16 bits) ----------------
__global__ void bf16cvt_kernel(const float* __restrict__ x, u16* __restrict__ xb) {
    const int i = (blockIdx.x * 256 + threadIdx.x) * 4;
    const float4 v = *reinterpret_cast<const float4*>(x + i);
    u16 o0 = f32_to_bf16(v.x), o1 = f32_to_bf16(v.y), o2 = f32_to_bf16(v.z), o3 = f32_to_bf16(v.w);
    *reinterpret_cast<ushort4*>(xb + i) = make_ushort4(o0, o1, o2, o3);
}

// ---------------- K1: sq[i] = ||x_i||^2 in f32 (one wave per row) ----------------
__global__ void row_norms_kernel(const float* __restrict__ x, float* __restrict__ sq) {
    const int wave = threadIdx.x >> 6;
    const int lane = threadIdx.x & 63;
    const int row = blockIdx.x * 4 + wave;
    const float2 v = *reinterpret_cast<const float2*>(x + (size_t)row * DIM + lane * 2);
    float s = v.x * v.x + v.y * v.y;
    #pragma unroll
    for (int off = 32; off; off >>= 1) s += __shfl_xor(s, off);
    if (lane == 0) sq[row] = s;
}

// ---------------- K2: init Boruvka state ----------------
__global__ void init_kernel(u16* __restrict__ comp, u64* __restrict__ best,
                            double* __restrict__ wsum) {
    const int i = blockIdx.x * 1024 + threadIdx.x;
    comp[i] = (u16)i;
    best[i] = MAXKEY;
    if (i == 0) *wsum = 0.0;
}

// ---------------- K3: D[i][j] = bf16(sqrt(max(sq_i+sq_j-2*xi.xj, eps))) via MFMA ----
// Triangular grid (by <= bx). 128x128 tile per 256-thread block (4 waves,
// each wave: 32 rows x 128 cols via 2x8 fragments of 16x16, K=128 in 4 steps).
// Mirror tile (bx,by) written from an LDS-transposed copy -> D bitwise symmetric,
// which the Boruvka hook 2-cycle invariant requires.
__global__ __launch_bounds__(256) void dist_mfma_kernel(const u16* __restrict__ xb,
                                                        const float* __restrict__ sq,
                                                        u16* __restrict__ Dm) {
    const int bx = blockIdx.x, by = blockIdx.y;
    if (by > bx) return;
    const int gi0 = by * 128, gj0 = bx * 128;
    const int tid = threadIdx.x;
    const int w = tid >> 6, l = tid & 63;
    const int lr = l & 15;   // row-in-A-frag / col-in-B-frag / col-in-C
    const int lk = l >> 4;   // k-group (8 elems each) / C row-group

    __shared__ u16 ldsT[128][136];  // transposed tile; stride 136 keeps 16B alignment

    f32x4 acc[2][8] = {};
    const u16* arow = xb + (size_t)(gi0 + w * 32 + lr) * DIM + lk * 8;
    const u16* brow = xb + (size_t)(gj0 + lr) * DIM + lk * 8;
    #pragma unroll
    for (int ks = 0; ks < 4; ++ks) {
        const short8 a0 = *reinterpret_cast<const short8*>(arow + ks * 32);
        const short8 a1 = *reinterpret_cast<const short8*>(arow + 16 * DIM + ks * 32);
        #pragma unroll
        for (int nj = 0; nj < 8; ++nj) {
            const short8 b = *reinterpret_cast<const short8*>(brow + (size_t)nj * 16 * DIM + ks * 32);
            acc[0][nj] = __builtin_amdgcn_mfma_f32_16x16x32_bf16(a0, b, acc[0][nj], 0, 0, 0);
            acc[1][nj] = __builtin_amdgcn_mfma_f32_16x16x32_bf16(a1, b, acc[1][nj], 0, 0, 0);
        }
    }

    // epilogue: C/D layout col=lane&15, row=(lane>>4)*4+reg  [m89-verified]
    #pragma unroll
    for (int mi = 0; mi < 2; ++mi) {
        #pragma unroll
        for (int nj = 0; nj < 8; ++nj) {
            const int cj = nj * 16 + lr;
            const float sj = sq[gj0 + cj];
            #pragma unroll
            for (int r = 0; r < 4; ++r) {
                const int ri = w * 32 + mi * 16 + lk * 4 + r;
                const float si = sq[gi0 + ri];
                const float d = sqrtf(fmaxf(si + sj - 2.0f * acc[mi][nj][r], EPSQ));
                const u16 bits = f32_to_bf16(d);
                Dm[(size_t)(gi0 + ri) * N + gj0 + cj] = bits;
                ldsT[cj][ri] = bits;
            }
        }
    }

    if (by == bx) return;  // diagonal tile is bitwise symmetric by itself
    __syncthreads();
    // cooperative coalesced mirror write: rows of ldsT -> tile (bx,by)
    const int row = tid >> 1, half = tid & 1;
    const uint4* src = reinterpret_cast<const uint4*>(&ldsT[row][half * 64]);
    uint4* dst = reinterpret_cast<uint4*>(Dm + (size_t)(gj0 + row) * N + gi0 + half * 64);
    #pragma unroll
    for (int k = 0; k < 8; ++k) dst[k] = src[k];
}

// ---------------- K4: per-row min outgoing edge -> atomicMin per component ----------------
// One wave per row. Key = (bf16 weight bits << 24) | canonical_edge_id(24b).
// Canonical id gives a global total order on undirected edges -> hook cycles are 2-cycles.
__global__ __launch_bounds__(256) void scan_kernel(const u16* __restrict__ Dm,
                                                   const u16* __restrict__ comp,
                                                   u64* __restrict__ best) {
    const int wave = threadIdx.x >> 6;
    const int lane = threadIdx.x & 63;
    const int i = blockIdx.x * 4 + wave;
    const int ci = comp[i];
    const u16* row = Dm + (size_t)i * N;
    u64 m = MAXKEY;
    #pragma unroll
    for (int k = 0; k < 8; ++k) {
        const int j0 = k * 512 + lane * 8;
        const ushort8 dv = *reinterpret_cast<const ushort8*>(row + j0);
        const ushort8 cv = *reinterpret_cast<const ushort8*>(comp + j0);
        #pragma unroll
        for (int e = 0; e < 8; ++e) {
            const int j = j0 + e;
            const int lo = i < j ? i : j;
            const int hi = i < j ? j : i;
            const u64 key = ((u64)dv[e] << 24) | (u64)((lo << 12) | hi);
            if (cv[e] != ci && key < m) m = key;
        }
    }
    #pragma unroll
    for (int off = 32; off; off >>= 1) {
        const u64 o = __shfl_xor(m, off);
        m = o < m ? o : m;
    }
    if (lane == 0 && m != MAXKEY) atomicMin(&best[ci], m);
}

// ---------------- K5: single-block hook/merge/compress ----------------
__launch_bounds__(1024, 1)
__global__ void merge_kernel(u64* __restrict__ best, u16* __restrict__ comp,
                             double* __restrict__ wsum, float* __restrict__ out,
                             int write_out) {
    __shared__ int parent[N];
    __shared__ double red[1024];
    const int tid = threadIdx.x;

    // --- hook: parent[c] = component of the other endpoint of best[c] ---
    u64 b[4];
    #pragma unroll
    for (int q = 0; q < 4; ++q) {
        const int c = tid + q * 1024;
        b[q] = best[c];
        int p = c;
        if (b[q] != MAXKEY) {
            const int id = (int)(b[q] & 0xFFFFFFu);
            const int a = id >> 12, e = id & 0xFFF;
            const int ca = comp[a], ce = comp[e];
            p = (ca == c) ? ce : ca;
        }
        parent[c] = p;
    }
    __syncthreads();

    // --- 2-cycle break (read pass, barrier, write pass: race-free) ---
    int np[4];
    #pragma unroll
    for (int q = 0; q < 4; ++q) {
        const int c = tid + q * 1024;
        const int p = parent[c];
        np[q] = (p != c && parent[p] == c && c < p) ? c : p;
    }
    __syncthreads();
    double myw = 0.0;
    #pragma unroll
    for (int q = 0; q < 4; ++q) {
        const int c = tid + q * 1024;
        parent[c] = np[q];
        if (np[q] != c)
            myw += (double)__uint_as_float((unsigned)((b[q] >> 24) & 0xFFFFu) << 16);
        best[c] = MAXKEY;  // reset for next round
    }

    // --- deterministic weight reduction (fixed tree order) ---
    red[tid] = myw;
    __syncthreads();
    #pragma unroll
    for (int s = 512; s; s >>= 1) {
        if (tid < s) red[tid] += red[tid + s];
        __syncthreads();
    }

    // --- pointer jumping: 12 iters covers depth 4096 (read/write split) ---
    for (int it = 0; it < 12; ++it) {
        #pragma unroll
        for (int q = 0; q < 4; ++q) {
            const int c = tid + q * 1024;
            np[q] = parent[parent[c]];
        }
        __syncthreads();
        #pragma unroll
        for (int q = 0; q < 4; ++q) parent[tid + q * 1024] = np[q];
        __syncthreads();
    }

    // --- comp update: old root -> new root ---
    #pragma unroll
    for (int q = 0; q < 4; ++q) {
        const int i = tid + q * 1024;
        comp[i] = (u16)parent[comp[i]];
    }

    if (tid == 0) {
        const double w = *wsum + red[0];
        *wsum = w;
        if (write_out) out[0] = (float)(WEIGHT * w / (double)(N - 1));
    }
}

extern "C" void kernel_launch(void* const* d_in, const int* in_sizes, int n_in,
                              void* d_out, int out_size, void* d_ws, size_t ws_size,
                              hipStream_t stream) {
    const float* x = (const float*)d_in[0];
    char* ws = (char*)d_ws;
    u16* Dm     = (u16*)ws;                                  // 32 MiB
    u16* xb     = (u16*)(ws + 33554432);                     // 1 MiB
    float* sq   = (float*)(ws + 34603008);                   // 16 KiB
    u16* comp   = (u16*)(ws + 34619392);                     // 8 KiB
    u64* best   = (u64*)(ws + 34627584);                     // 32 KiB
    double* wsum = (double*)(ws + 34660352);                 // 8 B
    float* out = (float*)d_out;

    bf16cvt_kernel<<<512, 256, 0, stream>>>(x, xb);
    row_norms_kernel<<<N / 4, 256, 0, stream>>>(x, sq);
    init_kernel<<<4, 1024, 0, stream>>>(comp, best, wsum);
    dim3 grd(32, 32);
    dist_mfma_kernel<<<grd, 256, 0, stream>>>(xb, sq, Dm);
    for (int r = 0; r < 12; ++r) {
        scan_kernel<<<N / 4, 256, 0, stream>>>(Dm, comp, best);
        merge_kernel<<<1, 1024, 0, stream>>>(best, comp, wsum, out, r == 11 ? 1 : 0);
    }
}

// Round 5
// 317.727 us; speedup vs baseline: 2.8213x; 1.1369x over previous
//
#include <hip/hip_runtime.h>
#include <hip/hip_bf16.h>
#include <cstdint>

#define N 4096
#define DIM 128
#define WEIGHT 0.01f
#define EPSQ 1e-12f
#define MAXKEY 0xFFFFFFFFFFFFFFFFull

typedef unsigned long long u64;
typedef unsigned int u32;
typedef unsigned short u16;
typedef short short8 __attribute__((ext_vector_type(8)));
typedef u16 us8 __attribute__((ext_vector_type(8)));
typedef float f32x4 __attribute__((ext_vector_type(4)));

__device__ __forceinline__ u16 f32_to_bf16(float f) {
    const unsigned u = __float_as_uint(f);
    return (u16)((u + 0x7FFFu + ((u >> 16) & 1u)) >> 16);  // round-to-nearest-even
}

// ---------------- K0: convert x (f32) -> xb (bf16 bits) ----------------
__global__ void bf16cvt_kernel(const float* __restrict__ x, u16* __restrict__ xb) {
    const int i = (blockIdx.x * 256 + threadIdx.x) * 4;
    const float4 v = *reinterpret_cast<const float4*>(x + i);
    *reinterpret_cast<ushort4*>(xb + i) =
        make_ushort4(f32_to_bf16(v.x), f32_to_bf16(v.y), f32_to_bf16(v.z), f32_to_bf16(v.w));
}

// ---------------- K1: sq[i] = ||x_i||^2 in f32 (one wave per row) ----------------
__global__ void row_norms_kernel(const float* __restrict__ x, float* __restrict__ sq) {
    const int wave = threadIdx.x >> 6;
    const int lane = threadIdx.x & 63;
    const int row = blockIdx.x * 4 + wave;
    const float2 v = *reinterpret_cast<const float2*>(x + (size_t)row * DIM + lane * 2);
    float s = v.x * v.x + v.y * v.y;
    #pragma unroll
    for (int off = 32; off; off >>= 1) s += __shfl_xor(s, off);
    if (lane == 0) sq[row] = s;
}

// ---------------- K2: init Boruvka state ----------------
__global__ void init_kernel(u16* __restrict__ comp, u64* __restrict__ best,
                            double* __restrict__ wsum, int* __restrict__ ncomp) {
    const int i = blockIdx.x * 1024 + threadIdx.x;
    comp[i] = (u16)i;
    best[i] = MAXKEY;
    if (i == 0) { *wsum = 0.0; *ncomp = N; }
}

// ---------------- K3: D = bf16(sqrt(max(sq_i+sq_j-2*xi.xj, eps))) via MFMA ----
// 64x64 tile / 256-thread block, triangular grid (by<=bx). Only 9 KB LDS ->
// 8 blocks/CU (latency hiding was the round-3 bottleneck: 10.6% occupancy).
// Mirror tile written from the LDS transpose -> D stays bitwise symmetric
// (required by the Boruvka hook 2-cycle invariant).
__global__ __launch_bounds__(256) void dist_mfma_kernel(const u16* __restrict__ xb,
                                                        const float* __restrict__ sq,
                                                        u16* __restrict__ Dm) {
    const int bx = blockIdx.x, by = blockIdx.y;
    if (by > bx) return;
    const int gi0 = by * 64, gj0 = bx * 64;
    const int tid = threadIdx.x;
    const int w = tid >> 6, l = tid & 63;
    const int lr = l & 15, lk = l >> 4;

    __shared__ u16 ldsT[64][72];  // [col][row], pad 72 keeps 8B align + spreads banks

    f32x4 acc[4] = {};
    const u16* arow = xb + (size_t)(gi0 + w * 16 + lr) * DIM + lk * 8;
    const u16* brow = xb + (size_t)(gj0 + lr) * DIM + lk * 8;
    #pragma unroll
    for (int ks = 0; ks < 4; ++ks) {
        const short8 a = *reinterpret_cast<const short8*>(arow + ks * 32);
        #pragma unroll
        for (int nj = 0; nj < 4; ++nj) {
            const short8 b = *reinterpret_cast<const short8*>(brow + (size_t)nj * 16 * DIM + ks * 32);
            acc[nj] = __builtin_amdgcn_mfma_f32_16x16x32_bf16(a, b, acc[nj], 0, 0, 0);
        }
    }

    // epilogue: C/D layout col=lane&15, row=(lane>>4)*4+reg [m89-verified]
    const int ri0 = w * 16 + lk * 4;
    #pragma unroll
    for (int nj = 0; nj < 4; ++nj) {
        const int cj = nj * 16 + lr;
        const float sj = sq[gj0 + cj];
        u64 pack = 0;
        #pragma unroll
        for (int r = 0; r < 4; ++r) {
            const float si = sq[gi0 + ri0 + r];
            const float d = sqrtf(fmaxf(si + sj - 2.0f * acc[nj][r], EPSQ));
            const u16 bits = f32_to_bf16(d);
            Dm[(size_t)(gi0 + ri0 + r) * N + gj0 + cj] = bits;
            pack |= (u64)bits << (16 * r);
        }
        *reinterpret_cast<u64*>(&ldsT[cj][ri0]) = pack;  // 4 contiguous rows: one b64
    }

    if (by == bx) return;  // diagonal tile symmetric by itself (uniform exit)
    __syncthreads();
    // cooperative coalesced mirror write: rows of ldsT -> tile (bx,by)
    const int row = tid >> 2, seg = tid & 3;
    const u16* src = &ldsT[row][seg * 16];
    u16* dst = Dm + (size_t)(gj0 + row) * N + gi0 + seg * 16;
    *reinterpret_cast<uint4*>(dst) = *reinterpret_cast<const uint4*>(src);
    *reinterpret_cast<uint4*>(dst + 8) = *reinterpret_cast<const uint4*>(src + 8);
}

// ---------------- K4: per-row min outgoing edge -> atomicMin per component ----------------
// One wave per row. Row-local u32 key (dbits<<12)|j: within fixed row i,
// canon(i,j) is strictly monotone in j, so min u32 key == min canonical key.
// Winner is re-packed as u64 (dbits<<24)|canonical_id for the global atomicMin
// (canonical order = global total order -> hook cycles are only 2-cycles).
__global__ __launch_bounds__(256) void scan_kernel(const u16* __restrict__ Dm,
                                                   const u16* __restrict__ comp,
                                                   u64* __restrict__ best,
                                                   const int* __restrict__ ncomp) {
    if (*ncomp == 1) return;  // converged: all later rounds are no-ops
    const int wave = threadIdx.x >> 6;
    const int lane = threadIdx.x & 63;
    const int i = blockIdx.x * 4 + wave;
    const u16 ci = comp[i];
    const u16* row = Dm + (size_t)i * N;
    u32 m = 0xFFFFFFFFu;
    #pragma unroll
    for (int k = 0; k < 8; ++k) {
        const int j0 = k * 512 + lane * 8;
        const us8 dv = *reinterpret_cast<const us8*>(row + j0);
        const us8 cv = *reinterpret_cast<const us8*>(comp + j0);
        #pragma unroll
        for (int e = 0; e < 8; ++e) {
            const u32 key = ((u32)dv[e] << 12) | (u32)(j0 + e);
            if (cv[e] != ci && key < m) m = key;  // diagonal j==i filtered by cv==ci
        }
    }
    #pragma unroll
    for (int off = 32; off; off >>= 1) {
        const u32 o = __shfl_xor(m, off);
        m = o < m ? o : m;
    }
    if (lane == 0 && m != 0xFFFFFFFFu) {
        const int j = (int)(m & 0xFFFu);
        const u32 d = m >> 12;
        const int lo = i < j ? i : j;
        const int hi = i < j ? j : i;
        const u64 key = ((u64)d << 24) | (u64)((lo << 12) | hi);
        atomicMin(&best[ci], key);
    }
}

// ---------------- K5: single-block hook/merge/compress + convergence count ----------------
__launch_bounds__(1024, 1)
__global__ void merge_kernel(u64* __restrict__ best, u16* __restrict__ comp,
                             double* __restrict__ wsum, float* __restrict__ out,
                             int* __restrict__ ncomp, int write_out) {
    const int tid = threadIdx.x;
    if (*ncomp == 1) {  // converged: wsum is final; just emit on the last round
        if (write_out && tid == 0) out[0] = (float)(WEIGHT * (*wsum) / (double)(N - 1));
        return;
    }
    __shared__ int parent[N];
    __shared__ double red[1024];
    __shared__ int redi[1024];

    // --- hook: parent[c] = component of the other endpoint of best[c] ---
    u64 b[4];
    #pragma unroll
    for (int q = 0; q < 4; ++q) {
        const int c = tid + q * 1024;
        b[q] = best[c];
        int p = c;
        if (b[q] != MAXKEY) {
            const int id = (int)(b[q] & 0xFFFFFFu);
            const int a = id >> 12, e = id & 0xFFF;
            const int ca = comp[a], ce = comp[e];
            p = (ca == c) ? ce : ca;
        }
        parent[c] = p;
    }
    __syncthreads();

    // --- 2-cycle break (read pass, barrier, write pass: race-free) ---
    int np[4];
    #pragma unroll
    for (int q = 0; q < 4; ++q) {
        const int c = tid + q * 1024;
        const int p = parent[c];
        np[q] = (p != c && parent[p] == c && c < p) ? c : p;
    }
    __syncthreads();
    double myw = 0.0;
    #pragma unroll
    for (int q = 0; q < 4; ++q) {
        const int c = tid + q * 1024;
        parent[c] = np[q];
        if (np[q] != c)
            myw += (double)__uint_as_float((unsigned)((b[q] >> 24) & 0xFFFFu) << 16);
        best[c] = MAXKEY;  // reset for next round
    }

    // --- deterministic weight reduction (fixed tree order) ---
    red[tid] = myw;
    __syncthreads();
    #pragma unroll
    for (int s = 512; s; s >>= 1) {
        if (tid < s) red[tid] += red[tid + s];
        __syncthreads();
    }
    double wred = 0.0;
    if (tid == 0) wred = red[0];

    // --- pointer jumping: 12 iters covers depth 4096 (read/write split) ---
    for (int it = 0; it < 12; ++it) {
        #pragma unroll
        for (int q = 0; q < 4; ++q) {
            const int c = tid + q * 1024;
            np[q] = parent[parent[c]];
        }
        __syncthreads();
        #pragma unroll
        for (int q = 0; q < 4; ++q) parent[tid + q * 1024] = np[q];
        __syncthreads();
    }

    // --- comp update (own-index RMW, race-free) + root count ---
    int rc = 0;
    #pragma unroll
    for (int q = 0; q < 4; ++q) {
        const int i = tid + q * 1024;
        rc += (parent[i] == i);
        comp[i] = (u16)parent[comp[i]];
    }
    redi[tid] = rc;
    __syncthreads();
    #pragma unroll
    for (int s = 512; s; s >>= 1) {
        if (tid < s) redi[tid] += redi[tid + s];
        __syncthreads();
    }

    if (tid == 0) {
        const double w = *wsum + wred;
        *wsum = w;
        *ncomp = redi[0];
        if (write_out) out[0] = (float)(WEIGHT * w / (double)(N - 1));
    }
}

extern "C" void kernel_launch(void* const* d_in, const int* in_sizes, int n_in,
                              void* d_out, int out_size, void* d_ws, size_t ws_size,
                              hipStream_t stream) {
    const float* x = (const float*)d_in[0];
    char* ws = (char*)d_ws;
    u16* Dm      = (u16*)ws;                                  // 32 MiB
    u16* xb      = (u16*)(ws + 33554432);                     // 1 MiB
    float* sq    = (float*)(ws + 34603008);                   // 16 KiB
    u16* comp    = (u16*)(ws + 34619392);                     // 8 KiB
    u64* best    = (u64*)(ws + 34627584);                     // 32 KiB
    double* wsum = (double*)(ws + 34660352);                  // 8 B
    int* ncomp   = (int*)(ws + 34660360);                     // 4 B
    float* out = (float*)d_out;

    bf16cvt_kernel<<<512, 256, 0, stream>>>(x, xb);
    row_norms_kernel<<<N / 4, 256, 0, stream>>>(x, sq);
    init_kernel<<<4, 1024, 0, stream>>>(comp, best, wsum, ncomp);
    dim3 grd(64, 64);
    dist_mfma_kernel<<<grd, 256, 0, stream>>>(xb, sq, Dm);
    for (int r = 0; r < 12; ++r) {
        scan_kernel<<<N / 4, 256, 0, stream>>>(Dm, comp, best, ncomp);
        merge_kernel<<<1, 1024, 0, stream>>>(best, comp, wsum, out, ncomp, r == 11 ? 1 : 0);
    }
}